// Round 1
// baseline (610.800 us; speedup 1.0000x reference)
//
#include <hip/hip_runtime.h>
#include <math.h>

// Problem constants: [b, seq, heads, head_dim] = [4, 8192, 16, 64], f32.
#define BB 4
#define SS 8192
#define HH 16
#define DDIM 64

// ws layout (floats):
//   [0, 6144)        sums[3][4][8][64]   (group, batch, qh(padded to 8), d)
//   X0 @ 6144        [4][8192][6][64]    group 0 pre-norm x
//   X1 after X0      [4][4096][5][64]    group 1
//   X2 after X1      [4][2048][5][64]    group 2
static const long X0_OFF = 6144;
static const long X0_SZ = 4L * 8192 * 6 * 64;
static const long X1_OFF = X0_OFF + X0_SZ;
static const long X1_SZ = 4L * 4096 * 5 * 64;
static const long X2_OFF = X1_OFF + X1_SZ;
static const long X2_SZ = 4L * 2048 * 5 * 64;
static const long WS_FLOATS = X2_OFF + X2_SZ;   // ~20.45M floats = 81.8 MB

__global__ __launch_bounds__(256) void k_zero_sums(float* ws) {
    int idx = blockIdx.x * 256 + threadIdx.x;
    if (idx < 6144) ws[idx] = 0.0f;
}

// Pass 1: per-position head-group attention. Thread = (pos, slot), slot<g active.
// Block = 32 positions x 8 slots. Writes pre-norm x to ws, accumulates global sums.
__global__ __launch_bounds__(256) void k_attn(const float* __restrict__ Q,
                                              const float* __restrict__ Kp,
                                              const float* __restrict__ Vp,
                                              float* __restrict__ ws) {
    __shared__ float psum[4][8][68];  // wave, slot, d (padded to kill bank conflicts)

    int bid = blockIdx.x;
    int gi, b, tile, g, r, off, hmin, J;
    long xoff;
    if (bid < 1024)      { gi = 0; b = bid >> 8; tile = bid & 255; g = 6; r = 1; off = 0; hmin = 0;  J = 8192; xoff = X0_OFF; }
    else if (bid < 1536) { gi = 1; bid -= 1024; b = bid >> 7; tile = bid & 127; g = 5; r = 2; off = 1; hmin = 5;  J = 4096; xoff = X1_OFF; }
    else                 { gi = 2; bid -= 1536; b = bid >> 6; tile = bid & 63;  g = 5; r = 4; off = 2; hmin = 10; J = 2048; xoff = X2_OFF; }

    const int t = threadIdx.x;
    const int slot = t & 7;       // query-head slot
    const int pl = t >> 3;        // position within tile (0..31)
    const int wave = t >> 6;
    const int j = tile * 32 + pl; // strided-view position index
    const int pos = off + j * r;  // real sequence position
    const int qh = (slot < g) ? slot : (g - 1);  // clamp idle slots to valid data
    const bool active = (slot < g);

    const long rowbase = (((long)b * SS + pos) * HH + hmin) * DDIM;
    const float4* q4p = (const float4*)(Q + rowbase + (long)qh * DDIM);
    const float4* k4p = (const float4*)(Kp + rowbase);  // + kh*16 float4
    const float4* v4p = (const float4*)(Vp + rowbase);

    // scores[kh] = q . k_kh  (over d=64)
    float sc[6];
#pragma unroll
    for (int kh = 0; kh < 6; ++kh) sc[kh] = 0.0f;
#pragma unroll
    for (int d4 = 0; d4 < 16; ++d4) {
        float4 q4 = q4p[d4];
#pragma unroll
        for (int kh = 0; kh < 6; ++kh) {
            if (kh < g) {
                float4 k4 = k4p[kh * 16 + d4];
                sc[kh] += q4.x * k4.x + q4.y * k4.y + q4.z * k4.z + q4.w * k4.w;
            }
        }
    }

    // softmax over kh of (scores * 1/sqrt(64))
    float mx = -3.4e38f;
#pragma unroll
    for (int kh = 0; kh < 6; ++kh)
        if (kh < g) mx = fmaxf(mx, sc[kh]);
    float at[6];
    float den = 0.0f;
#pragma unroll
    for (int kh = 0; kh < 6; ++kh) {
        if (kh < g) { at[kh] = expf((sc[kh] - mx) * 0.125f); den += at[kh]; }
        else at[kh] = 0.0f;
    }
    const float rden = 1.0f / den;
#pragma unroll
    for (int kh = 0; kh < 6; ++kh) at[kh] *= rden;

    float* xrow = ws + xoff + (((long)b * J + j) * g + qh) * DDIM;

    // x = attn @ V, streamed per float4 of d; reduce over wave's 8 positions
#pragma unroll
    for (int d4 = 0; d4 < 16; ++d4) {
        float4 a = make_float4(0.f, 0.f, 0.f, 0.f);
#pragma unroll
        for (int kh = 0; kh < 6; ++kh) {
            if (kh < g) {
                float4 v4 = v4p[kh * 16 + d4];
                a.x += at[kh] * v4.x; a.y += at[kh] * v4.y;
                a.z += at[kh] * v4.z; a.w += at[kh] * v4.w;
            }
        }
        if (active) ((float4*)xrow)[d4] = a;

        float4 red = active ? a : make_float4(0.f, 0.f, 0.f, 0.f);
#pragma unroll
        for (int m = 8; m <= 32; m <<= 1) {  // reduce over position bits of lane
            red.x += __shfl_xor(red.x, m, 64);
            red.y += __shfl_xor(red.y, m, 64);
            red.z += __shfl_xor(red.z, m, 64);
            red.w += __shfl_xor(red.w, m, 64);
        }
        if ((t & 63) < 8) {  // pos-in-wave == 0 lanes; lane == slot
            psum[wave][slot][d4 * 4 + 0] = red.x;
            psum[wave][slot][d4 * 4 + 1] = red.y;
            psum[wave][slot][d4 * 4 + 2] = red.z;
            psum[wave][slot][d4 * 4 + 3] = red.w;
        }
    }
    __syncthreads();

    // combine 4 waves, one global atomic per (slot, d) per block
#pragma unroll
    for (int idx = t; idx < 512; idx += 256) {
        int s2 = idx >> 6, dd = idx & 63;
        if (s2 < g) {
            float v = psum[0][s2][dd] + psum[1][s2][dd] + psum[2][s2][dd] + psum[3][s2][dd];
            unsafeAtomicAdd(ws + ((long)(gi * 4 + b) * 8 + s2) * 64 + dd, v);
        }
    }
}

// Pass 2: gather. Block = one (b, pos): 16 heads x 16 float4 of d. Fully coalesced.
__global__ __launch_bounds__(256) void k_out(const float* __restrict__ ws,
                                             float* __restrict__ out) {
    const int t = threadIdx.x;
    const long bid = blockIdx.x;
    const int dd4 = t & 15;
    const int h = t >> 4;
    const int pos = (int)(bid & 8191);
    const int b = (int)(bid >> 13);

    float4 r = make_float4(0.f, 0.f, 0.f, 0.f);

    if (h < 6) {  // group 0: all positions, heads 0..5
        float4 x = ((const float4*)(ws + X0_OFF + (((long)b * 8192 + pos) * 6 + h) * 64))[dd4];
        float4 s = ((const float4*)(ws + ((long)(0 * 4 + b) * 8 + h) * 64))[dd4];
        r.x += x.x / s.x; r.y += x.y / s.y; r.z += x.z / s.z; r.w += x.w / s.w;
    }
    if (h >= 5 && h <= 9 && (pos & 1) == 1) {  // group 1: odd positions, heads 5..9
        int jj = pos >> 1, qh = h - 5;
        float4 x = ((const float4*)(ws + X1_OFF + (((long)b * 4096 + jj) * 5 + qh) * 64))[dd4];
        float4 s = ((const float4*)(ws + ((long)(1 * 4 + b) * 8 + qh) * 64))[dd4];
        r.x += x.x / s.x; r.y += x.y / s.y; r.z += x.z / s.z; r.w += x.w / s.w;
    }
    if (h >= 10 && h <= 14 && (pos & 3) == 2) {  // group 2: pos%4==2, heads 10..14
        int jj = pos >> 2, qh = h - 10;
        float4 x = ((const float4*)(ws + X2_OFF + (((long)b * 2048 + jj) * 5 + qh) * 64))[dd4];
        float4 s = ((const float4*)(ws + ((long)(2 * 4 + b) * 8 + qh) * 64))[dd4];
        r.x += x.x / s.x; r.y += x.y / s.y; r.z += x.z / s.z; r.w += x.w / s.w;
    }

    const float third = 1.0f / 3.0f;
    r.x *= third; r.y *= third; r.z *= third; r.w *= third;
    ((float4*)out)[bid * 256 + t] = r;
}

extern "C" void kernel_launch(void* const* d_in, const int* in_sizes, int n_in,
                              void* d_out, int out_size, void* d_ws, size_t ws_size,
                              hipStream_t stream) {
    const float* Q = (const float*)d_in[0];
    const float* K = (const float*)d_in[1];
    const float* V = (const float*)d_in[2];
    float* ws = (float*)d_ws;
    float* out = (float*)d_out;

    if (ws_size < (size_t)WS_FLOATS * sizeof(float)) return;  // need ~82 MB scratch

    k_zero_sums<<<24, 256, 0, stream>>>(ws);
    k_attn<<<1792, 256, 0, stream>>>(Q, K, V, ws);
    k_out<<<32768, 256, 0, stream>>>(ws, out);
}

// Round 2
// 403.880 us; speedup vs baseline: 1.5123x; 1.5123x over previous
//
#include <hip/hip_runtime.h>
#include <math.h>

// Problem constants: [b, seq, heads, head_dim] = [4, 8192, 16, 64], f32.
#define BB 4
#define SS 8192
#define HH 16
#define DDIM 64

// ws layout (floats):
//   [0, 6144)        sums[3][4][8][64]   (group, batch, qh(padded to 8), d)
//   X0 @ 6144        [4][8192][6][64]    group 0 pre-norm x
//   X1 after X0      [4][4096][5][64]    group 1
//   X2 after X1      [4][2048][5][64]    group 2
static const long X0_OFF = 6144;
static const long X0_SZ = 4L * 8192 * 6 * 64;
static const long X1_OFF = X0_OFF + X0_SZ;
static const long X1_SZ = 4L * 4096 * 5 * 64;
static const long X2_OFF = X1_OFF + X1_SZ;
static const long X2_SZ = 4L * 2048 * 5 * 64;
static const long WS_FLOATS = X2_OFF + X2_SZ;   // ~20.45M floats = 81.8 MB

__global__ __launch_bounds__(256) void k_zero_sums(float* ws) {
    int idx = blockIdx.x * 256 + threadIdx.x;
    if (idx < 6144) ws[idx] = 0.0f;
}

// after k_attn: sums -> 1/sums (unused slots become inf, never read)
__global__ __launch_bounds__(256) void k_recip(float* ws) {
    int idx = blockIdx.x * 256 + threadIdx.x;
    if (idx < 6144) ws[idx] = __frcp_rn(ws[idx]);
}

__device__ __forceinline__ float4 shfl_xor4(float4 v, int m) {
    return make_float4(__shfl_xor(v.x, m, 64), __shfl_xor(v.y, m, 64),
                       __shfl_xor(v.z, m, 64), __shfl_xor(v.w, m, 64));
}

// Pass 1: per-position head-group attention.
// Lane layout: lane = (posInWave<<4) | d4  -> 16 lanes own one position's 64-d.
// All global reads/writes are dense contiguous 256B bursts per (pos, head).
// Block = 256 threads = 16 consecutive positions.
__global__ __launch_bounds__(256) void k_attn(const float* __restrict__ Q,
                                              const float* __restrict__ Kp,
                                              const float* __restrict__ Vp,
                                              float* __restrict__ ws) {
    __shared__ __align__(16) float psum[4][6][64];  // wave, qh, d

    int bid = blockIdx.x;
    int gi, b, tile, g, r, off, hmin, J;
    long xoff;
    if (bid < 2048)      { gi = 0; b = bid >> 9; tile = bid & 511; g = 6; r = 1; off = 0; hmin = 0;  J = 8192; xoff = X0_OFF; }
    else if (bid < 3072) { gi = 1; bid -= 2048; b = bid >> 8; tile = bid & 255; g = 5; r = 2; off = 1; hmin = 5;  J = 4096; xoff = X1_OFF; }
    else                 { gi = 2; bid -= 3072; b = bid >> 7; tile = bid & 127; g = 5; r = 4; off = 2; hmin = 10; J = 2048; xoff = X2_OFF; }

    const int t = threadIdx.x;
    const int lane = t & 63;
    const int wave = t >> 6;
    const int d4 = t & 15;          // which float4 of the 64-d row
    const int pIdx = t >> 4;        // position within block (0..15)
    const int j = tile * 16 + pIdx; // strided-view position index
    const int pos = off + j * r;    // real sequence position

    const long rowbase = (((long)b * SS + pos) * HH + hmin) * DDIM;
    const float4* q4p = (const float4*)(Q + rowbase);
    const float4* k4p = (const float4*)(Kp + rowbase);
    const float4* v4p = (const float4*)(Vp + rowbase);

    // Dense loads: lane d4 reads float4 #d4 of each head row (256B/16-lane burst)
    float4 q4[6], k4[6], v4[6];
#pragma unroll
    for (int hh = 0; hh < 6; ++hh) {
        if (hh < g) {
            q4[hh] = q4p[hh * 16 + d4];
            k4[hh] = k4p[hh * 16 + d4];
            v4[hh] = v4p[hh * 16 + d4];
        } else {
            q4[hh] = make_float4(0.f, 0.f, 0.f, 0.f);
            k4[hh] = q4[hh];
            v4[hh] = q4[hh];
        }
    }

    // scores p[qh][kh] = q_qh . k_kh : per-lane partial dot + 16-lane butterfly
    float p[6][6];
#pragma unroll
    for (int qh = 0; qh < 6; ++qh) {
#pragma unroll
        for (int kh = 0; kh < 6; ++kh) {
            if (qh < g && kh < g) {
                float s = q4[qh].x * k4[kh].x + q4[qh].y * k4[kh].y +
                          q4[qh].z * k4[kh].z + q4[qh].w * k4[kh].w;
#pragma unroll
                for (int m = 1; m <= 8; m <<= 1) s += __shfl_xor(s, m, 64);
                p[qh][kh] = s;
            } else {
                p[qh][kh] = 0.0f;
            }
        }
    }

    // softmax over kh per qh (duplicated across the 16 d4 lanes; cheap)
#pragma unroll
    for (int qh = 0; qh < 6; ++qh) {
        if (qh >= g) continue;
        float mx = -3.4e38f;
#pragma unroll
        for (int kh = 0; kh < 6; ++kh)
            if (kh < g) mx = fmaxf(mx, p[qh][kh]);
        float den = 0.0f;
#pragma unroll
        for (int kh = 0; kh < 6; ++kh) {
            if (kh < g) { p[qh][kh] = __expf((p[qh][kh] - mx) * 0.125f); den += p[qh][kh]; }
        }
        float rden = 1.0f / den;
#pragma unroll
        for (int kh = 0; kh < 6; ++kh) p[qh][kh] *= rden;
    }

    // x = attn @ V ; dense 256B stores; butterfly over 4 positions for norm sum
    float4* xrow = (float4*)(ws + xoff + (((long)b * J + j) * g) * DDIM);
#pragma unroll
    for (int qh = 0; qh < 6; ++qh) {
        if (qh >= g) continue;
        float4 o = make_float4(0.f, 0.f, 0.f, 0.f);
#pragma unroll
        for (int kh = 0; kh < 6; ++kh) {
            if (kh < g) {
                o.x += p[qh][kh] * v4[kh].x; o.y += p[qh][kh] * v4[kh].y;
                o.z += p[qh][kh] * v4[kh].z; o.w += p[qh][kh] * v4[kh].w;
            }
        }
        xrow[qh * 16 + d4] = o;

        // sum over the wave's 4 positions (lane bits 4,5)
        float4 red = o;
        red = shfl_xor4(red, 16);
        {
            float4 tmp = shfl_xor4(red, 32);
            red.x += tmp.x; red.y += tmp.y; red.z += tmp.z; red.w += tmp.w;
        }
        // note: shfl_xor4(red,16) above REPLACED red; fix: do proper add
        // (kept correct below by recomputing)
        red = o;
#pragma unroll
        for (int m = 16; m <= 32; m <<= 1) {
            float4 tmp = shfl_xor4(red, m);
            red.x += tmp.x; red.y += tmp.y; red.z += tmp.z; red.w += tmp.w;
        }
        if (lane < 16) ((float4*)&psum[wave][qh][0])[d4] = red;
    }
    __syncthreads();

    // combine 4 waves; one atomic per (qh,d) per block
    for (int idx = t; idx < g * 64; idx += 256) {
        int qh = idx >> 6, dd = idx & 63;
        float v = psum[0][qh][dd] + psum[1][qh][dd] + psum[2][qh][dd] + psum[3][qh][dd];
        unsafeAtomicAdd(ws + ((long)(gi * 4 + b) * 8 + qh) * 64 + dd, v);
    }
}

// Pass 2: gather + normalize. Block = 8 consecutive (b,pos); 32KB contiguous writes.
__global__ __launch_bounds__(256) void k_out(const float* __restrict__ ws,
                                             float* __restrict__ out) {
    const int t = threadIdx.x;
    const int bid = blockIdx.x;
    const int dd4 = t & 15;
    const int h = t >> 4;
    const int b = bid >> 10;           // 1024 position-blocks per batch
    const int pos0 = (bid & 1023) * 8;

    // reciprocal sums: depend only on (group,b,head) -> hoist out of pos loop
    float4 rs0 = make_float4(0.f, 0.f, 0.f, 0.f), rs1 = rs0, rs2 = rs0;
    if (h < 6)
        rs0 = ((const float4*)(ws + ((long)(0 * 4 + b) * 8 + h) * 64))[dd4];
    if (h >= 5 && h <= 9)
        rs1 = ((const float4*)(ws + ((long)(1 * 4 + b) * 8 + (h - 5)) * 64))[dd4];
    if (h >= 10 && h <= 14)
        rs2 = ((const float4*)(ws + ((long)(2 * 4 + b) * 8 + (h - 10)) * 64))[dd4];

#pragma unroll
    for (int pp = 0; pp < 8; ++pp) {
        const int pos = pos0 + pp;
        float4 r = make_float4(0.f, 0.f, 0.f, 0.f);

        if (h < 6) {  // group 0: all positions, heads 0..5
            float4 x = ((const float4*)(ws + X0_OFF + (((long)b * 8192 + pos) * 6 + h) * 64))[dd4];
            r.x += x.x * rs0.x; r.y += x.y * rs0.y; r.z += x.z * rs0.z; r.w += x.w * rs0.w;
        }
        if (h >= 5 && h <= 9 && (pos & 1) == 1) {  // group 1: odd positions
            int jj = pos >> 1;
            float4 x = ((const float4*)(ws + X1_OFF + (((long)b * 4096 + jj) * 5 + (h - 5)) * 64))[dd4];
            r.x += x.x * rs1.x; r.y += x.y * rs1.y; r.z += x.z * rs1.z; r.w += x.w * rs1.w;
        }
        if (h >= 10 && h <= 14 && (pos & 3) == 2) {  // group 2: pos%4==2
            int jj = pos >> 2;
            float4 x = ((const float4*)(ws + X2_OFF + (((long)b * 2048 + jj) * 5 + (h - 10)) * 64))[dd4];
            r.x += x.x * rs2.x; r.y += x.y * rs2.y; r.z += x.z * rs2.z; r.w += x.w * rs2.w;
        }

        const float third = 1.0f / 3.0f;
        r.x *= third; r.y *= third; r.z *= third; r.w *= third;
        ((float4*)out)[((long)(b * 8192 + pos)) * 256 + t] = r;
    }
}

extern "C" void kernel_launch(void* const* d_in, const int* in_sizes, int n_in,
                              void* d_out, int out_size, void* d_ws, size_t ws_size,
                              hipStream_t stream) {
    const float* Q = (const float*)d_in[0];
    const float* K = (const float*)d_in[1];
    const float* V = (const float*)d_in[2];
    float* ws = (float*)d_ws;
    float* out = (float*)d_out;

    if (ws_size < (size_t)WS_FLOATS * sizeof(float)) return;  // need ~82 MB scratch

    k_zero_sums<<<24, 256, 0, stream>>>(ws);
    k_attn<<<3584, 256, 0, stream>>>(Q, K, V, ws);
    k_recip<<<24, 256, 0, stream>>>(ws);
    k_out<<<4096, 256, 0, stream>>>(ws, out);
}